// Round 4
// baseline (75.198 us; speedup 1.0000x reference)
//
#include <hip/hip_runtime.h>

typedef unsigned short u16;
typedef short bf16x8 __attribute__((ext_vector_type(8)));
typedef u16 u16x8 __attribute__((ext_vector_type(8)));
typedef float f32x4 __attribute__((ext_vector_type(4)));

#define K_DIM 256
#define L_DIM 4096
#define NBATCH 4

static __device__ __forceinline__ u16 f2bf(float f) {
    unsigned u = __float_as_uint(f);
    unsigned r = (u + 0x7FFFu + ((u >> 16) & 1u)) >> 16;
    return (u16)r;
}
static __device__ __forceinline__ float bf2f(u16 v) {
    return __uint_as_float(((unsigned)v) << 16);
}

#define GLOAD16(g, l) __builtin_amdgcn_global_load_lds( \
    (const __attribute__((address_space(1))) void*)(g), \
    (__attribute__((address_space(3))) void*)(l), 16, 0, 0)

// ---------------------------------------------------------------------------
// K1: depthwise 3x3 conv + transpose + bf16 cast; weight casts folded in as
// extra blocks (blockIdx.x == 4).
// ---------------------------------------------------------------------------
__global__ __launch_bounds__(256) void prep_kernel(
    const float* __restrict__ x, const float* __restrict__ dw_w,
    const float* __restrict__ dw_b, const float* __restrict__ pin_w,
    const float* __restrict__ pw_w, const float* __restrict__ pout_w,
    u16* __restrict__ xb_t, u16* __restrict__ dwc_t,
    u16* __restrict__ pin_wb, u16* __restrict__ pw_wb,
    u16* __restrict__ pout_wb)
{
    if (blockIdx.x == 4) {                      // weight-cast blocks
        if (blockIdx.z != 0) return;
        const int end = (blockIdx.y + 1) * 2560;
        for (int k = blockIdx.y * 2560 + threadIdx.x; k < end; k += 256) {
            if (k < 65536) pin_wb[k] = f2bf(pin_w[k]);
            else if (k < 98304) {
                int j = k - 65536;
                pw_wb[j] = ((j >> 8) < 112) ? f2bf(pw_w[j]) : (u16)0;
            } else {
                int j = k - 98304;
                pout_wb[j] = f2bf(pout_w[j]);
            }
        }
        return;
    }

    __shared__ u16 tx_[64][66];
    __shared__ u16 td_[64][66];
    const int c0 = blockIdx.x * 64, h = blockIdx.y, n = blockIdx.z;
    const int t = threadIdx.x, w = t & 63, cq = t >> 6;
    const float* xn = x + (size_t)n * 256 * L_DIM;
    const int wm = (w > 0) ? w - 1 : 0;
    const int wp = (w < 63) ? w + 1 : 63;
    const float lv = (w > 0) ? 1.f : 0.f;
    const float rv = (w < 63) ? 1.f : 0.f;

    for (int i = 0; i < 16; ++i) {
        const int cl = i * 4 + cq, c = c0 + cl;
        const float* xc = xn + (size_t)c * L_DIM;
        const float* w9 = dw_w + c * 9;
        float s = dw_b[c];
        #pragma unroll
        for (int dy = 0; dy < 3; ++dy) {
            const int hh = h + dy - 1;
            if (hh < 0 || hh > 63) continue;   // block-uniform branch
            const float* row = xc + hh * 64;
            s = fmaf(row[wm] * lv, w9[dy*3 + 0], s);
            s = fmaf(row[w],       w9[dy*3 + 1], s);
            s = fmaf(row[wp] * rv, w9[dy*3 + 2], s);
        }
        tx_[w][cl] = f2bf(xc[h*64 + w]);
        td_[w][cl] = f2bf(s);
    }
    __syncthreads();
    const int cc = t & 63;
    for (int j = 0; j < 16; ++j) {
        const int wl = j * 4 + cq;
        const size_t o = ((size_t)n * L_DIM + h * 64 + wl) * 256 + c0 + cc;
        xb_t[o]  = tx_[wl][cc];
        dwc_t[o] = td_[wl][cc];
    }
}

// ---------------------------------------------------------------------------
// K2: pin + pw GEMMs in one dispatch (unchanged from round 2).
// ---------------------------------------------------------------------------
__global__ __launch_bounds__(256) void gemm_dual(
    const u16* __restrict__ xb_t, const u16* __restrict__ dwc_t,
    const u16* __restrict__ pin_wb, const u16* __restrict__ pw_wb,
    const float* __restrict__ pin_b, const float* __restrict__ pw_b,
    u16* __restrict__ val_b, float* __restrict__ omb)
{
    __shared__ u16 lds[16384];
    const int bx = blockIdx.x;
    const bool isPw = (bx == 2);
    const u16* Ag = isPw ? dwc_t : xb_t;
    const u16* Bg = isPw ? pw_wb : pin_wb;
    const float* bias = isPw ? pw_b : pin_b;
    const int n0 = isPw ? 0 : bx * 128;
    const int Ncols = isPw ? 112 : 256;
    const int ldC = isPw ? 112 : 256;
    const int m0 = blockIdx.y * 128;

    const int t = threadIdx.x;
    const int wave = t >> 6, lane = t & 63;
    const int lr = lane & 15, lk = lane >> 4;
    const int wr = wave >> 1, wc = wave & 1;
    const int wbase = wave << 10;

    const int srow = t >> 2;
    const int scol = (t & 3) * 8;
    const u16* ga0 = Ag + (size_t)(m0 + srow)      * K_DIM + scol;
    const u16* ga1 = Ag + (size_t)(m0 + 64 + srow) * K_DIM + scol;
    const u16* gb0 = Bg + (size_t)(n0 + srow)      * K_DIM + scol;
    const u16* gb1 = Bg + (size_t)(n0 + 64 + srow) * K_DIM + scol;

    f32x4 acc[4][4];
    #pragma unroll
    for (int m = 0; m < 4; ++m)
        #pragma unroll
        for (int n = 0; n < 4; ++n) acc[m][n] = (f32x4){0.f, 0.f, 0.f, 0.f};

    auto stage = [&](int b, int kt) {
        const int ko = kt * 32;
        char* base = (char*)lds + b * 16384 + wbase;
        GLOAD16(ga0 + ko, base);
        GLOAD16(ga1 + ko, base + 4096);
        GLOAD16(gb0 + ko, base + 8192);
        GLOAD16(gb1 + ko, base + 12288);
    };

    stage(0, 0);
    asm volatile("s_waitcnt vmcnt(0)" ::: "memory");
    __syncthreads();

    for (int kt = 0; kt < 8; ++kt) {
        const int cur = kt & 1;
        if (kt < 7) stage(cur ^ 1, kt + 1);
        const char* la = (const char*)lds + cur * 16384;
        const char* lb = la + 8192;
        bf16x8 af[4], bfr[4];
        #pragma unroll
        for (int m = 0; m < 4; ++m)
            af[m] = *(const bf16x8*)(la + ((wr*64 + m*16 + lr) * 32 + lk * 8) * 2);
        #pragma unroll
        for (int n = 0; n < 4; ++n)
            bfr[n] = *(const bf16x8*)(lb + ((wc*64 + n*16 + lr) * 32 + lk * 8) * 2);
        #pragma unroll
        for (int m = 0; m < 4; ++m)
            #pragma unroll
            for (int n = 0; n < 4; ++n)
                acc[m][n] = __builtin_amdgcn_mfma_f32_16x16x32_bf16(
                    af[m], bfr[n], acc[m][n], 0, 0, 0);
        asm volatile("s_waitcnt vmcnt(0)" ::: "memory");
        __syncthreads();
    }

    #pragma unroll
    for (int m = 0; m < 4; ++m) {
        #pragma unroll
        for (int n = 0; n < 4; ++n) {
            const int col = n0 + wc*64 + n*16 + lr;
            if (col < Ncols) {
                const float bv = bias[col];
                #pragma unroll
                for (int r = 0; r < 4; ++r) {
                    const int row = m0 + wr*64 + m*16 + lk*4 + r;
                    const float o = acc[m][n][r] + bv;
                    const size_t off = (size_t)row * ldC + col;
                    if (isPw) omb[off] = o;
                    else      val_b[off] = f2bf(o);
                }
            }
        }
    }
}

// ---------------------------------------------------------------------------
// K3: fused deformable gather (LDS val tiles) + output projection.
// Block = one image row (64 positions), 512 threads.
// Gather: group tiles vt[5 rows][64 ix][64 ch] staged via global_load_lds;
// waves 0-3 handle group a, waves 4-7 group b; 16 ch/lane.
// Out-of-tile-but-valid samples (large offsets) fall back to global loads.
// ---------------------------------------------------------------------------
__global__ __launch_bounds__(512, 2) void gather_pout(
    const float* __restrict__ om, const u16* __restrict__ val,
    const u16* __restrict__ pout_wb, const float* __restrict__ pout_b,
    float* __restrict__ out)
{
    __shared__ u16 vt[2][20480];     // per buffer: [5][64][64] bf16 = 40 KB
    __shared__ u16 sacc[64][264];
    const int blk = blockIdx.x;            // 0..255
    const int n = blk >> 6;
    const int h = blk & 63;
    const int l0 = h * 64;
    const int t = threadIdx.x;
    const u16* valn = val + (size_t)n * L_DIM * 256;

    auto stage_tile = [&](int buf, int g) {
        const int ix = t >> 3, oct = t & 7;
        #pragma unroll
        for (int ty = 0; ty < 5; ++ty) {
            const int row = min(max(h - 2 + ty, 0), 63);
            const u16* src = valn + (size_t)(row * 64 + ix) * 256 + g * 64 + oct * 8;
            GLOAD16(src, (char*)&vt[buf][0] + ty * 8192 + t * 16);
        }
    };

    stage_tile(0, 0);
    stage_tile(1, 1);
    asm volatile("s_waitcnt vmcnt(0)" ::: "memory");
    __syncthreads();

    const int wave = t >> 6, lane = t & 63;
    const int posw = (wave & 3) * 16 + (lane >> 2);   // w coordinate 0..63
    const int cl = (lane & 3) * 16;                    // channel base in group
    const float xb = (float)posw - 1.f;
    const float ybase = (float)h - 1.f;

    for (int half = 0; half < 2; ++half) {
        const int g = half * 2 + (wave >> 2);
        const u16* vbuf = &vt[wave >> 2][0];
        const float* omp = om + ((size_t)n * L_DIM + l0 + posw) * 112 + g * 27;

        float a[16];
        #pragma unroll
        for (int j = 0; j < 16; ++j) a[j] = 0.f;

        #pragma unroll 3
        for (int p = 0; p < 9; ++p) {
            const float ox = omp[p*3 + 0];
            const float oy = omp[p*3 + 1];
            const float mk = omp[p*3 + 2];
            const float py = ybase + (float)(p / 3) + oy;
            const float px = xb + (float)(p % 3) + ox;
            const float y0 = floorf(py), x0 = floorf(px);
            const float fy = py - y0, fx = px - x0;
            const int iy0 = (int)y0, ix0 = (int)x0;
            const float wy[2] = {mk * (1.f - fy), mk * fy};
            const float wx[2] = {1.f - fx, fx};
            #pragma unroll
            for (int q = 0; q < 4; ++q) {
                const int dy = q >> 1, dx = q & 1;
                const int iy = iy0 + dy, ix = ix0 + dx;
                const bool ok = ((unsigned)iy < 64u) & ((unsigned)ix < 64u);
                float wgt = ok ? wy[dy] * wx[dx] : 0.f;
                const int ty = iy - (h - 2);
                const bool intile = ((unsigned)ty < 5u);
                const int tyc = min(max(ty, 0), 4);
                const int ixc = min(max(ix, 0), 63);
                const u16* lp = vbuf + ((tyc * 64 + ixc) * 64 + cl);
                u16x8 v0 = *(const u16x8*)lp;
                u16x8 v1 = *(const u16x8*)(lp + 8);
                if (__any(ok && !intile)) {      // rare: big offsets
                    const int iyc = min(max(iy, 0), 63);
                    const u16* gp = valn + (size_t)(iyc * 64 + ixc) * 256 + g * 64 + cl;
                    const u16x8 gv0 = *(const u16x8*)gp;
                    const u16x8 gv1 = *(const u16x8*)(gp + 8);
                    if (ok && !intile) { v0 = gv0; v1 = gv1; }
                }
                #pragma unroll
                for (int j = 0; j < 8; ++j) a[j]     = fmaf(wgt, bf2f(v0[j]), a[j]);
                #pragma unroll
                for (int j = 0; j < 8; ++j) a[j + 8] = fmaf(wgt, bf2f(v1[j]), a[j + 8]);
            }
        }
        u16x8 o0, o1;
        #pragma unroll
        for (int j = 0; j < 8; ++j) { o0[j] = f2bf(a[j]); o1[j] = f2bf(a[j + 8]); }
        *(u16x8*)(&sacc[posw][g*64 + cl])     = o0;
        *(u16x8*)(&sacc[posw][g*64 + cl + 8]) = o1;

        if (half == 0) {
            __syncthreads();                     // vt reads done
            stage_tile(0, 2);
            stage_tile(1, 3);
            asm volatile("s_waitcnt vmcnt(0)" ::: "memory");
            __syncthreads();
        }
    }
    __syncthreads();

    // ---- Phase B: pout GEMM (A = pout_wb from L2, B = LDS sacc tile) ----
    const int lr = lane & 15, lk = lane >> 4;
    const int wr = wave >> 1, wc = wave & 1;

    f32x4 acc[4][2];
    #pragma unroll
    for (int m = 0; m < 4; ++m)
        #pragma unroll
        for (int nn = 0; nn < 2; ++nn) acc[m][nn] = (f32x4){0.f, 0.f, 0.f, 0.f};

    #pragma unroll
    for (int kt = 0; kt < 8; ++kt) {
        bf16x8 af[4], bfr[2];
        #pragma unroll
        for (int m = 0; m < 4; ++m)
            af[m] = *(const bf16x8*)(pout_wb +
                (size_t)(wr*64 + m*16 + lr) * K_DIM + kt*32 + lk*8);
        #pragma unroll
        for (int nn = 0; nn < 2; ++nn)
            bfr[nn] = *(const bf16x8*)(&sacc[wc*32 + nn*16 + lr][kt*32 + lk*8]);
        #pragma unroll
        for (int m = 0; m < 4; ++m)
            #pragma unroll
            for (int nn = 0; nn < 2; ++nn)
                acc[m][nn] = __builtin_amdgcn_mfma_f32_16x16x32_bf16(
                    af[m], bfr[nn], acc[m][nn], 0, 0, 0);
    }

    float* outn = out + (size_t)n * 256 * L_DIM;
    #pragma unroll
    for (int m = 0; m < 4; ++m) {
        #pragma unroll
        for (int nn = 0; nn < 2; ++nn) {
            const int col = l0 + wc*32 + nn*16 + lr;
            #pragma unroll
            for (int r = 0; r < 4; ++r) {
                const int row = wr*64 + m*16 + lk*4 + r;
                outn[(size_t)row * L_DIM + col] = acc[m][nn][r] + pout_b[row];
            }
        }
    }
}

// ---------------------------------------------------------------------------
extern "C" void kernel_launch(void* const* d_in, const int* in_sizes, int n_in,
                              void* d_out, int out_size, void* d_ws, size_t ws_size,
                              hipStream_t stream) {
    const float* x      = (const float*)d_in[0];
    const float* dw_w   = (const float*)d_in[1];
    const float* dw_b   = (const float*)d_in[2];
    const float* pw_w   = (const float*)d_in[3];
    const float* pw_b   = (const float*)d_in[4];
    const float* pin_w  = (const float*)d_in[5];
    const float* pin_b  = (const float*)d_in[6];
    const float* pout_w = (const float*)d_in[7];
    const float* pout_b = (const float*)d_in[8];
    float* out = (float*)d_out;

    char* ws = (char*)d_ws;
    u16*   xb_t    = (u16*)ws;                      //  8,388,608
    u16*   dwc_t   = (u16*)(ws + 8388608);          //  8,388,608
    u16*   val_b   = (u16*)(ws + 16777216);         //  8,388,608
    float* omb     = (float*)(ws + 25165824);       //  7,340,032
    u16*   pin_wb  = (u16*)(ws + 32505856);         //    131,072
    u16*   pw_wb   = (u16*)(ws + 32636928);         //     65,536 (128 rows)
    u16*   pout_wb = (u16*)(ws + 32702464);         //    131,072

    // K1: depthwise conv + transpose-cast + weight casts
    prep_kernel<<<dim3(5, 64, NBATCH), 256, 0, stream>>>(
        x, dw_w, dw_b, pin_w, pw_w, pout_w,
        xb_t, dwc_t, pin_wb, pw_wb, pout_wb);

    // K2: val = pin(x) [bf16], om = pw(dwc) [fp32]
    gemm_dual<<<dim3(3, 128), 256, 0, stream>>>(
        xb_t, dwc_t, pin_wb, pw_wb, pin_b, pw_b, val_b, omb);

    // K3: deformable gather (LDS tiles) + pout projection
    gather_pout<<<dim3(256), 512, 0, stream>>>(
        omb, val_b, pout_wb, pout_b, out);
}